// Round 17
// baseline (272.866 us; speedup 1.0000x reference)
//
#include <hip/hip_runtime.h>

#define NN 50000
#define NE 500000
#define NGR 64
#define HD 128
#define INF 5
#define BN_EPS 1e-5f
#define BM 64
#define SCB 128
#define SCT 256
#define SCH ((NN + SCB - 1) / SCB)
#define PP 16             // pooling parts per graph
#define NWFU (3 * 8 * 4 * 64 * 4)  // wfrag uints: L*t*s*lane*4
#define PAD8(c) (((c) + 7) & ~7)
#define AGB 512           // agg blocks
#define AGW (AGB * 16)    // agg waves total

typedef __attribute__((ext_vector_type(8))) short short8v;
typedef __attribute__((ext_vector_type(4))) float f32x4;

// ---------- bf16 helpers ----------
__device__ __forceinline__ float bflo(unsigned u) { return __uint_as_float(u << 16); }
__device__ __forceinline__ float bfhi(unsigned u) { return __uint_as_float(u & 0xffff0000u); }
__device__ __forceinline__ unsigned bfpack(float a, float b) {
    unsigned ua = __float_as_uint(a), ub = __float_as_uint(b);
    ua = (ua + 0x7fffu + ((ua >> 16) & 1u)) >> 16;
    ub = (ub + 0x7fffu + ((ub >> 16) & 1u)) >> 16;
    return ua | (ub << 16);
}
__device__ __forceinline__ unsigned short bf1(float a) {
    unsigned ua = __float_as_uint(a);
    return (unsigned short)((ua + 0x7fffu + ((ua >> 16) & 1u)) >> 16);
}

// ---------- init: fill=0, stats=0, pack conv weights into MFMA B-fragment order ----------
__global__ void k_init(int* fill, float* stats, const float* __restrict__ conv_ws,
                       unsigned* __restrict__ wbf) {
    int i = blockIdx.x * 256 + threadIdx.x;
    if (i < NN) fill[i] = 0;
    if (i < 4 * 2 * HD) stats[i] = 0.f;
    if (i < NWFU) {
        int inner = i & 3;
        int u4 = i >> 2;
        int lane = u4 & 63;
        int rest = u4 >> 6;
        int s = rest & 3, tt = (rest >> 2) & 7, L = rest >> 5;
        int col = tt * 16 + (lane & 15);
        int k = s * 32 + (lane >> 4) * 8 + inner * 2;
        const float* Wl = conv_ws + (size_t)L * HD * HD;
        wbf[i] = bfpack(Wl[k * HD + col], Wl[(k + 1) * HD + col]);
    }
}

// ---------- pass A: per-edge bucket position (the ONLY atomic pass) ----------
__global__ void k_pos(const int* __restrict__ ei, int* __restrict__ fill,
                      int* __restrict__ pos) {
    int e = blockIdx.x * 256 + threadIdx.x;
    if (e < NE) pos[e] = atomicAdd(&fill[ei[NE + e]], 1);
}

// ---------- hierarchical scan of PADDED fill -> col_ptr ----------
__global__ void k_scan1(const int* __restrict__ cnt, int* __restrict__ bsum) {
    __shared__ int sm[SCT];
    int b = blockIdx.x, t = threadIdx.x;
    int lo = b * SCH, hi = min(lo + SCH, NN);
    int s = 0;
    for (int i = lo + t; i < hi; i += SCT) s += PAD8(cnt[i]);
    sm[t] = s;
    __syncthreads();
    for (int off = SCT / 2; off > 0; off >>= 1) {
        if (t < off) sm[t] += sm[t + off];
        __syncthreads();
    }
    if (t == 0) bsum[b] = sm[0];
}

// block 0: scan of block sums; block 1: graph boundaries
__global__ void k_scan2_gb(const int* __restrict__ bsum, int* __restrict__ boff,
                           const int* __restrict__ batch, int* __restrict__ gstart) {
    int t = threadIdx.x;  // 128
    if (blockIdx.x == 1) {
        int g = t;
        if (g > NGR) return;
        int lo = 0, hi = NN;
        while (lo < hi) {
            int mid = (lo + hi) >> 1;
            if (batch[mid] < g) lo = mid + 1;
            else hi = mid;
        }
        gstart[g] = lo;
        return;
    }
    __shared__ int sm[SCB];
    sm[t] = bsum[t];
    __syncthreads();
    for (int off = 1; off < SCB; off <<= 1) {
        int v = (t >= off) ? sm[t - off] : 0;
        __syncthreads();
        sm[t] += v;
        __syncthreads();
    }
    boff[t] = (t == 0) ? 0 : sm[t - 1];
    if (t == SCB - 1) boff[SCB] = sm[SCB - 1];
}

__global__ void k_scan3(const int* __restrict__ cnt, const int* __restrict__ boff,
                        int* __restrict__ col_ptr) {
    __shared__ int sm[SCT];
    int b = blockIdx.x, t = threadIdx.x;
    int lo = b * SCH, hi = min(lo + SCH, NN);
    int e0 = lo + 2 * t, e1 = e0 + 1;
    int c0 = (e0 < hi) ? PAD8(cnt[e0]) : 0;
    int c1 = (e1 < hi) ? PAD8(cnt[e1]) : 0;
    sm[t] = c0 + c1;
    __syncthreads();
    for (int off = 1; off < SCT; off <<= 1) {
        int v = (t >= off) ? sm[t - off] : 0;
        __syncthreads();
        sm[t] += v;
        __syncthreads();
    }
    int base = boff[b] + ((t == 0) ? 0 : sm[t - 1]);
    if (e0 < hi) col_ptr[e0] = base;
    if (e1 < hi) col_ptr[e1] = base + c0;
    if (b == SCB - 1 && t == SCT - 1) col_ptr[NN] = boff[SCB];
}

// ---------- pass B: scatter {src, ea} as int2, no atomics ----------
__global__ void k_scatter(const int* __restrict__ ei, const float* __restrict__ ea,
                          const int* __restrict__ col_ptr, const int* __restrict__ pos,
                          int2* __restrict__ sw) {
    int e = blockIdx.x * 256 + threadIdx.x;
    if (e >= NE) return;
    int c = ei[NE + e];
    int p = col_ptr[c] + pos[e];
    sw[p] = make_int2(ei[e], __float_as_int(ea[e]));
}

// ---------- weighted degree (real count) + write zero pads ----------
__global__ void k_degsum(const int* __restrict__ col_ptr, const int* __restrict__ cnt,
                         int2* __restrict__ sw, float* __restrict__ dinv) {
    int i = blockIdx.x * 256 + threadIdx.x;
    if (i >= NN) return;
    int beg = col_ptr[i], mid = beg + cnt[i], end = col_ptr[i + 1];
    float s = 1.0f;  // self-loop weight
    for (int p = beg; p < mid; p++) s += __int_as_float(sw[p].y);
    for (int p = mid; p < end; p++) sw[p] = make_int2(0, 0);  // pad: src=0, w=0
    dinv[i] = rsqrtf(s);
}

// ---------- layer-0 transform: m = x @ W0 (K=5), bf16 output ----------
__global__ void k_gemm0(const float* __restrict__ x, const float* __restrict__ W,
                        unsigned* __restrict__ m32) {
    __shared__ float Ws[INF][HD];
    int t = threadIdx.x;  // 256
    for (int i = t; i < INF * HD; i += 256) ((float*)Ws)[i] = W[i];
    __syncthreads();
    int row = blockIdx.x * 4 + (t >> 6);
    if (row >= NN) return;
    int lane = t & 63;
    int c0 = 2 * lane;
    float xv[INF];
#pragma unroll
    for (int k = 0; k < INF; k++) xv[k] = x[row * INF + k];
    float a0 = 0.f, a1 = 0.f;
#pragma unroll
    for (int k = 0; k < INF; k++) {
        a0 += xv[k] * Ws[k][c0];
        a1 += xv[k] * Ws[k][c0 + 1];
    }
    m32[(size_t)row * 64 + lane] = bfpack(a0, a1);
}

// ---------- fused BN(prev)+SiLU + MFMA GEMM ----------
__global__ __launch_bounds__(256) void k_gemm128(
    const unsigned* __restrict__ h32, const float* __restrict__ stats,
    const float* __restrict__ gamma, const float* __restrict__ beta,
    const uint4* __restrict__ wfrag, unsigned short* __restrict__ m16) {
    __shared__ __align__(16) unsigned hs[64 * 64];  // 16 KB packed bf16
    __shared__ float sc[HD], sh[HD];
    int t = threadIdx.x;
    int r0 = blockIdx.x * BM;
    const float invn = 1.0f / NN;

    if (t < HD) {
        float mu = stats[t] * invn;
        float var = stats[HD + t] * invn - mu * mu;
        float s = gamma[t] * rsqrtf(var + BN_EPS);
        sc[t] = s;
        sh[t] = beta[t] - mu * s;
    }
    __syncthreads();

#pragma unroll
    for (int j = 0; j < 8; j++) {
        int g = j * 256 + t;      // uint2 slot 0..2047
        int r = g >> 5;           // row 0..63
        int u2 = g & 31;          // uint2 within row
        uint2 v = make_uint2(0u, 0u);
        if (r0 + r < NN) v = ((const uint2*)h32)[(size_t)(r0 + r) * 32 + u2];
        int c = u2 * 4;
        float y0 = sc[c] * bflo(v.x) + sh[c];
        float y1 = sc[c + 1] * bfhi(v.x) + sh[c + 1];
        float y2 = sc[c + 2] * bflo(v.y) + sh[c + 2];
        float y3 = sc[c + 3] * bfhi(v.y) + sh[c + 3];
        y0 = y0 / (1.f + __expf(-y0));
        y1 = y1 / (1.f + __expf(-y1));
        y2 = y2 / (1.f + __expf(-y2));
        y3 = y3 / (1.f + __expf(-y3));
        int slot = u2 >> 1, inner = (u2 & 1) * 2;
        int addr = r * 64 + ((slot ^ (r & 7)) << 2) + inner;
        hs[addr] = bfpack(y0, y1);
        hs[addr + 1] = bfpack(y2, y3);
    }
    __syncthreads();

    int w = t >> 6, l = t & 63;
    int lr = l & 15, lg = l >> 4;
    f32x4 acc[8];
#pragma unroll
    for (int i = 0; i < 8; i++) acc[i] = (f32x4){0.f, 0.f, 0.f, 0.f};

#pragma unroll
    for (int s = 0; s < 4; s++) {  // K steps of 32
        int arow = w * 16 + lr;
        int q = s * 4 + lg;
        short8v af = *reinterpret_cast<const short8v*>(
            &hs[arow * 64 + ((q ^ (arow & 7)) << 2)]);
#pragma unroll
        for (int tt = 0; tt < 8; tt++) {
            short8v bf = *reinterpret_cast<const short8v*>(&wfrag[(tt * 4 + s) * 64 + l]);
            acc[tt] = __builtin_amdgcn_mfma_f32_16x16x32_bf16(af, bf, acc[tt], 0, 0, 0);
        }
    }

    int baserow = r0 + w * 16 + lg * 4;
#pragma unroll
    for (int tt = 0; tt < 8; tt++) {
        int col = tt * 16 + lr;
#pragma unroll
        for (int reg = 0; reg < 4; reg++) {
            int row = baserow + reg;
            if (row < NN) m16[(size_t)row * HD + col] = bf1(acc[tt][reg]);
        }
    }
}

// ---------- sparse aggregation + fused BN stats: scalar edge records,
// next-node metadata prefetch ----------
template <bool NORM>
__global__ __launch_bounds__(1024, 8) void k_agg(
    const unsigned* __restrict__ m32, const int* __restrict__ col_ptr,
    int2* __restrict__ sw, const float* __restrict__ dinv,
    const float* __restrict__ bias, unsigned* __restrict__ hpre32,
    float* __restrict__ stats) {
    int t = threadIdx.x;
    int w = t >> 6, lane = t & 63;
    int gwave = blockIdx.x * 16 + w;
    float2 b = ((const float2*)bias)[lane];
    float ss0 = 0.f, ss1 = 0.f, sq0 = 0.f, sq1 = 0.f;

    int node = gwave;
    if (node < NN) {
        int beg = __builtin_amdgcn_readfirstlane(col_ptr[node]);
        int end = __builtin_amdgcn_readfirstlane(col_ptr[node + 1]);
        float di = __uint_as_float(
            __builtin_amdgcn_readfirstlane(__float_as_uint(dinv[node])));
        while (true) {
            // prefetch next node's metadata (scalar loads overlap current gathers)
            int nxt = node + AGW;
            int nbeg = 0, nend = 0;
            float ndi = 0.f;
            if (nxt < NN) {
                nbeg = __builtin_amdgcn_readfirstlane(col_ptr[nxt]);
                nend = __builtin_amdgcn_readfirstlane(col_ptr[nxt + 1]);
                ndi = __uint_as_float(
                    __builtin_amdgcn_readfirstlane(__float_as_uint(dinv[nxt])));
            }
            unsigned sv = m32[(size_t)node * 64 + lane];
            float a0 = di * di * bflo(sv);
            float a1 = di * di * bfhi(sv);
            for (int p = beg; p < end; p += 8) {
                // 4 x int4 = 8 edge records from a wave-uniform address
                const int4* sp = (const int4*)(sw + p);
                int4 q0 = sp[0], q1 = sp[1], q2 = sp[2], q3 = sp[3];
                int s0 = __builtin_amdgcn_readfirstlane(q0.x);
                int s1 = __builtin_amdgcn_readfirstlane(q0.z);
                int s2 = __builtin_amdgcn_readfirstlane(q1.x);
                int s3 = __builtin_amdgcn_readfirstlane(q1.z);
                int s4 = __builtin_amdgcn_readfirstlane(q2.x);
                int s5 = __builtin_amdgcn_readfirstlane(q2.z);
                int s6 = __builtin_amdgcn_readfirstlane(q3.x);
                int s7 = __builtin_amdgcn_readfirstlane(q3.z);
                unsigned v0 = m32[(size_t)s0 * 64 + lane];
                unsigned v1 = m32[(size_t)s1 * 64 + lane];
                unsigned v2 = m32[(size_t)s2 * 64 + lane];
                unsigned v3 = m32[(size_t)s3 * 64 + lane];
                unsigned v4 = m32[(size_t)s4 * 64 + lane];
                unsigned v5 = m32[(size_t)s5 * 64 + lane];
                unsigned v6 = m32[(size_t)s6 * 64 + lane];
                unsigned v7 = m32[(size_t)s7 * 64 + lane];
                float w0 = __int_as_float(__builtin_amdgcn_readfirstlane(q0.y));
                float w1 = __int_as_float(__builtin_amdgcn_readfirstlane(q0.w));
                float w2 = __int_as_float(__builtin_amdgcn_readfirstlane(q1.y));
                float w3 = __int_as_float(__builtin_amdgcn_readfirstlane(q1.w));
                float w4 = __int_as_float(__builtin_amdgcn_readfirstlane(q2.y));
                float w5 = __int_as_float(__builtin_amdgcn_readfirstlane(q2.w));
                float w6 = __int_as_float(__builtin_amdgcn_readfirstlane(q3.y));
                float w7 = __int_as_float(__builtin_amdgcn_readfirstlane(q3.w));
                if (NORM) {
                    w0 = dinv[s0] * w0 * di;
                    w1 = dinv[s1] * w1 * di;
                    w2 = dinv[s2] * w2 * di;
                    w3 = dinv[s3] * w3 * di;
                    w4 = dinv[s4] * w4 * di;
                    w5 = dinv[s5] * w5 * di;
                    w6 = dinv[s6] * w6 * di;
                    w7 = dinv[s7] * w7 * di;
                    if (lane == 0) {  // write normalized weights back for layers 1..3
                        sw[p].y = __float_as_int(w0);
                        sw[p + 1].y = __float_as_int(w1);
                        sw[p + 2].y = __float_as_int(w2);
                        sw[p + 3].y = __float_as_int(w3);
                        sw[p + 4].y = __float_as_int(w4);
                        sw[p + 5].y = __float_as_int(w5);
                        sw[p + 6].y = __float_as_int(w6);
                        sw[p + 7].y = __float_as_int(w7);
                    }
                }
                a0 += w0 * bflo(v0) + w1 * bflo(v1) + w2 * bflo(v2) + w3 * bflo(v3);
                a1 += w0 * bfhi(v0) + w1 * bfhi(v1) + w2 * bfhi(v2) + w3 * bfhi(v3);
                a0 += w4 * bflo(v4) + w5 * bflo(v5) + w6 * bflo(v6) + w7 * bflo(v7);
                a1 += w4 * bfhi(v4) + w5 * bfhi(v5) + w6 * bfhi(v6) + w7 * bfhi(v7);
            }
            unsigned pk = bfpack(a0 + b.x, a1 + b.y);
            hpre32[(size_t)node * 64 + lane] = pk;
            float r0 = bflo(pk), r1 = bfhi(pk);
            ss0 += r0; sq0 += r0 * r0;
            ss1 += r1; sq1 += r1 * r1;
            if (nxt >= NN) break;
            node = nxt;
            beg = nbeg;
            end = nend;
            di = ndi;
        }
    }

    // fused BN stats: 16-wave LDS combine, then one atomic per stat slot
    __shared__ float lsum[16][HD];
    __shared__ float lsqr[16][HD];
    lsum[w][2 * lane] = ss0;
    lsum[w][2 * lane + 1] = ss1;
    lsqr[w][2 * lane] = sq0;
    lsqr[w][2 * lane + 1] = sq1;
    __syncthreads();
    if (t < HD) {
        float s = 0.f;
#pragma unroll
        for (int i = 0; i < 16; i++) s += lsum[i][t];
        atomicAdd(&stats[t], s);
    } else if (t < 2 * HD) {
        int c = t - HD;
        float q = 0.f;
#pragma unroll
        for (int i = 0; i < 16; i++) q += lsqr[i][c];
        atomicAdd(&stats[HD + c], q);
    }
}

// ---------- pooling stage 1 (fused final BN+SiLU), bf16 input ----------
__global__ void k_poolp(const unsigned* __restrict__ h32, const float* __restrict__ stats,
                        const float* __restrict__ gamma, const float* __restrict__ beta,
                        const int* __restrict__ gstart, float* __restrict__ ppool) {
    int g = blockIdx.x / PP, p = blockIdx.x % PP;
    int t = threadIdx.x;          // 256
    int c4 = t & 31;              // 4-channel group
    int ro = t >> 5;
    const float invn = 1.0f / NN;
    float sc[4], sh[4];
#pragma unroll
    for (int q = 0; q < 4; q++) {
        int c = c4 * 4 + q;
        float mu = stats[c] * invn;
        float var = stats[HD + c] * invn - mu * mu;
        float s = gamma[c] * rsqrtf(var + BN_EPS);
        sc[q] = s;
        sh[q] = beta[c] - mu * s;
    }
    int beg = gstart[g], end = gstart[g + 1];
    const uint2* h2 = (const uint2*)h32;
    float4 acc = make_float4(0.f, 0.f, 0.f, 0.f);
    for (int r = beg + p * 8 + ro; r < end; r += PP * 8) {
        uint2 u = h2[(size_t)r * 32 + c4];
        float vals[4] = {bflo(u.x), bfhi(u.x), bflo(u.y), bfhi(u.y)};
#pragma unroll
        for (int q = 0; q < 4; q++) {
            float y = sc[q] * vals[q] + sh[q];
            (&acc.x)[q] += y / (1.f + __expf(-y));
        }
    }
    __shared__ float4 sm[256];
    sm[t] = acc;
    __syncthreads();
    if (t < 128) {
        float4 o = sm[t + 128];
        sm[t].x += o.x; sm[t].y += o.y; sm[t].z += o.z; sm[t].w += o.w;
    }
    __syncthreads();
    if (t < 64) {
        float4 o = sm[t + 64];
        sm[t].x += o.x; sm[t].y += o.y; sm[t].z += o.z; sm[t].w += o.w;
    }
    __syncthreads();
    if (t < 32) {
        float4 o = sm[t + 32];
        float4 r = sm[t];
        r.x += o.x; r.y += o.y; r.z += o.z; r.w += o.w;
        ((float4*)ppool)[(size_t)blockIdx.x * 32 + t] = r;
    }
}

// ---------- pooling stage 2 + head MLP fused ----------
__global__ void k_pool_head(const float* __restrict__ ppool, const int* __restrict__ gstart,
                            const float* __restrict__ fc1w, const float* __restrict__ fc1b,
                            const float* __restrict__ fc2w, const float* __restrict__ fc2b,
                            float* __restrict__ out) {
    int g = blockIdx.x;
    int t = threadIdx.x;  // 128
    __shared__ float pa[HD];
    float s = 0.f;
    for (int p = 0; p < PP; p++) s += ppool[(size_t)(g * PP + p) * HD + t];
    float cnt = (float)(gstart[g + 1] - gstart[g]);
    pa[t] = s / fmaxf(cnt, 1.0f);
    __syncthreads();
    if (t < 64) {
        float a = fc1b[t];
        for (int k = 0; k < HD; k++) a += pa[k] * fc1w[k * 64 + t];
        a = a / (1.f + __expf(-a));  // SiLU
        float v = a * fc2w[t];
        for (int off = 32; off > 0; off >>= 1) v += __shfl_down(v, off);
        if (t == 0) out[g] = 1.f / (1.f + __expf(-(v + fc2b[0])));
    }
}

extern "C" void kernel_launch(void* const* d_in, const int* in_sizes, int n_in,
                              void* d_out, int out_size, void* d_ws, size_t ws_size,
                              hipStream_t stream) {
    const float* x = (const float*)d_in[0];
    const int* ei = (const int*)d_in[1];  // [2, E]: row=ei[0..E), col=ei[E..2E)
    const float* ea = (const float*)d_in[2];
    const int* batch = (const int*)d_in[3];
    const float* conv0_w = (const float*)d_in[5];
    const float* conv0_b = (const float*)d_in[6];
    const float* conv_ws = (const float*)d_in[7];
    const float* conv_bs = (const float*)d_in[8];
    const float* bn_gamma = (const float*)d_in[9];
    const float* bn_beta = (const float*)d_in[10];
    const float* fc1w = (const float*)d_in[11];
    const float* fc1b = (const float*)d_in[12];
    const float* fc2w = (const float*)d_in[13];
    const float* fc2b = (const float*)d_in[14];
    float* out = (float*)d_out;

    char* ws = (char*)d_ws;
    size_t off = 0;
    auto alloc = [&](size_t bytes) -> char* {
        char* p = ws + off;
        off = (off + bytes + 255) & ~(size_t)255;
        return p;
    };
    float* dinv = (float*)alloc(NN * 4);
    int* fill = (int*)alloc(NN * 4);
    int* col_ptr = (int*)alloc((NN + 1) * 4);
    int* pos = (int*)alloc(NE * 4);
    int2* sw = (int2*)alloc(((size_t)NE + 8 * NN) * 8);  // padded CSR
    unsigned* mbuf = (unsigned*)alloc((size_t)NN * HD * 2);
    unsigned* hA = (unsigned*)alloc((size_t)NN * HD * 2);
    unsigned* hB = (unsigned*)alloc((size_t)NN * HD * 2);
    unsigned* wbf = (unsigned*)alloc((size_t)NWFU * 4);
    float* stats = (float*)alloc(4 * 2 * HD * 4);
    float* ppool = (float*)alloc((size_t)NGR * PP * HD * 4);
    int* gstart = (int*)alloc((NGR + 1) * 4);
    int* bsum = (int*)alloc(SCB * 4);
    int* boff = (int*)alloc((SCB + 1) * 4);

    k_init<<<(NN + 255) / 256, 256, 0, stream>>>(fill, stats, conv_ws, wbf);
    k_pos<<<(NE + 255) / 256, 256, 0, stream>>>(ei, fill, pos);
    k_scan1<<<SCB, SCT, 0, stream>>>(fill, bsum);
    k_scan2_gb<<<2, SCB, 0, stream>>>(bsum, boff, batch, gstart);
    k_scan3<<<SCB, SCT, 0, stream>>>(fill, boff, col_ptr);
    k_scatter<<<(NE + 255) / 256, 256, 0, stream>>>(ei, ea, col_ptr, pos, sw);
    k_degsum<<<(NN + 255) / 256, 256, 0, stream>>>(col_ptr, fill, sw, dinv);

    float* st0 = stats;
    float* st1 = stats + 2 * HD;
    float* st2 = stats + 4 * HD;
    float* st3 = stats + 6 * HD;
    const int NG128 = (NN + BM - 1) / BM;
    const uint4* wf = (const uint4*)wbf;  // 2048 uint4 per layer

    // L0 (agg fuses weight normalization + BN0 stats)
    k_gemm0<<<(NN + 3) / 4, 256, 0, stream>>>(x, conv0_w, mbuf);
    k_agg<true><<<AGB, 1024, 0, stream>>>(mbuf, col_ptr, sw, dinv, conv0_b, hA, st0);
    // L1
    k_gemm128<<<NG128, 256, 0, stream>>>(hA, st0, bn_gamma, bn_beta, wf,
                                         (unsigned short*)mbuf);
    k_agg<false><<<AGB, 1024, 0, stream>>>(mbuf, col_ptr, sw, dinv, conv_bs, hB, st1);
    // L2
    k_gemm128<<<NG128, 256, 0, stream>>>(hB, st1, bn_gamma + HD, bn_beta + HD, wf + 2048,
                                         (unsigned short*)mbuf);
    k_agg<false><<<AGB, 1024, 0, stream>>>(mbuf, col_ptr, sw, dinv, conv_bs + HD, hA, st2);
    // L3
    k_gemm128<<<NG128, 256, 0, stream>>>(hA, st2, bn_gamma + 2 * HD, bn_beta + 2 * HD,
                                         wf + 4096, (unsigned short*)mbuf);
    k_agg<false><<<AGB, 1024, 0, stream>>>(mbuf, col_ptr, sw, dinv, conv_bs + 2 * HD, hB,
                                           st3);
    // fused final BN+SiLU + pool + head
    k_poolp<<<NGR * PP, 256, 0, stream>>>(hB, st3, bn_gamma + 3 * HD, bn_beta + 3 * HD,
                                          gstart, ppool);
    k_pool_head<<<NGR, HD, 0, stream>>>(ppool, gstart, fc1w, fc1b, fc2w, fc2b, out);
}

// Round 18
// 265.612 us; speedup vs baseline: 1.0273x; 1.0273x over previous
//
#include <hip/hip_runtime.h>

#define NN 50000
#define NE 500000
#define NGR 64
#define HD 128
#define INF 5
#define BN_EPS 1e-5f
#define BM 64
#define SCB 128
#define SCT 256
#define SCH ((NN + SCB - 1) / SCB)
#define PP 16             // pooling parts per graph
#define NWFU (3 * 8 * 4 * 64 * 4)  // wfrag uints: L*t*s*lane*4
#define PAD8(c) (((c) + 7) & ~7)
#define AGB 512           // agg blocks
#define AGW (AGB * 16)    // agg waves total

typedef __attribute__((ext_vector_type(8))) short short8v;
typedef __attribute__((ext_vector_type(4))) float f32x4;

// ---------- bf16 helpers ----------
__device__ __forceinline__ float bflo(unsigned u) { return __uint_as_float(u << 16); }
__device__ __forceinline__ float bfhi(unsigned u) { return __uint_as_float(u & 0xffff0000u); }
__device__ __forceinline__ unsigned bfpack(float a, float b) {
    unsigned ua = __float_as_uint(a), ub = __float_as_uint(b);
    ua = (ua + 0x7fffu + ((ua >> 16) & 1u)) >> 16;
    ub = (ub + 0x7fffu + ((ub >> 16) & 1u)) >> 16;
    return ua | (ub << 16);
}
__device__ __forceinline__ unsigned short bf1(float a) {
    unsigned ua = __float_as_uint(a);
    return (unsigned short)((ua + 0x7fffu + ((ua >> 16) & 1u)) >> 16);
}

// ---------- init: fill=0, stats=0, pack conv weights into MFMA B-fragment order ----------
__global__ void k_init(int* fill, float* stats, const float* __restrict__ conv_ws,
                       unsigned* __restrict__ wbf) {
    int i = blockIdx.x * 256 + threadIdx.x;
    if (i < NN) fill[i] = 0;
    if (i < 4 * 2 * HD) stats[i] = 0.f;
    if (i < NWFU) {
        int inner = i & 3;
        int u4 = i >> 2;
        int lane = u4 & 63;
        int rest = u4 >> 6;
        int s = rest & 3, tt = (rest >> 2) & 7, L = rest >> 5;
        int col = tt * 16 + (lane & 15);
        int k = s * 32 + (lane >> 4) * 8 + inner * 2;
        const float* Wl = conv_ws + (size_t)L * HD * HD;
        wbf[i] = bfpack(Wl[k * HD + col], Wl[(k + 1) * HD + col]);
    }
}

// ---------- pass A: per-edge bucket position (the ONLY atomic pass) ----------
__global__ void k_pos(const int* __restrict__ ei, int* __restrict__ fill,
                      int* __restrict__ pos) {
    int e = blockIdx.x * 256 + threadIdx.x;
    if (e < NE) pos[e] = atomicAdd(&fill[ei[NE + e]], 1);
}

// ---------- hierarchical scan of PADDED fill -> col_ptr ----------
__global__ void k_scan1(const int* __restrict__ cnt, int* __restrict__ bsum) {
    __shared__ int sm[SCT];
    int b = blockIdx.x, t = threadIdx.x;
    int lo = b * SCH, hi = min(lo + SCH, NN);
    int s = 0;
    for (int i = lo + t; i < hi; i += SCT) s += PAD8(cnt[i]);
    sm[t] = s;
    __syncthreads();
    for (int off = SCT / 2; off > 0; off >>= 1) {
        if (t < off) sm[t] += sm[t + off];
        __syncthreads();
    }
    if (t == 0) bsum[b] = sm[0];
}

// block 0: scan of block sums; block 1: graph boundaries
__global__ void k_scan2_gb(const int* __restrict__ bsum, int* __restrict__ boff,
                           const int* __restrict__ batch, int* __restrict__ gstart) {
    int t = threadIdx.x;  // 128
    if (blockIdx.x == 1) {
        int g = t;
        if (g > NGR) return;
        int lo = 0, hi = NN;
        while (lo < hi) {
            int mid = (lo + hi) >> 1;
            if (batch[mid] < g) lo = mid + 1;
            else hi = mid;
        }
        gstart[g] = lo;
        return;
    }
    __shared__ int sm[SCB];
    sm[t] = bsum[t];
    __syncthreads();
    for (int off = 1; off < SCB; off <<= 1) {
        int v = (t >= off) ? sm[t - off] : 0;
        __syncthreads();
        sm[t] += v;
        __syncthreads();
    }
    boff[t] = (t == 0) ? 0 : sm[t - 1];
    if (t == SCB - 1) boff[SCB] = sm[SCB - 1];
}

__global__ void k_scan3(const int* __restrict__ cnt, const int* __restrict__ boff,
                        int* __restrict__ col_ptr) {
    __shared__ int sm[SCT];
    int b = blockIdx.x, t = threadIdx.x;
    int lo = b * SCH, hi = min(lo + SCH, NN);
    int e0 = lo + 2 * t, e1 = e0 + 1;
    int c0 = (e0 < hi) ? PAD8(cnt[e0]) : 0;
    int c1 = (e1 < hi) ? PAD8(cnt[e1]) : 0;
    sm[t] = c0 + c1;
    __syncthreads();
    for (int off = 1; off < SCT; off <<= 1) {
        int v = (t >= off) ? sm[t - off] : 0;
        __syncthreads();
        sm[t] += v;
        __syncthreads();
    }
    int base = boff[b] + ((t == 0) ? 0 : sm[t - 1]);
    if (e0 < hi) col_ptr[e0] = base;
    if (e1 < hi) col_ptr[e1] = base + c0;
    if (b == SCB - 1 && t == SCT - 1) col_ptr[NN] = boff[SCB];
}

// ---------- pass B: scatter {src, ea} as int2, no atomics ----------
__global__ void k_scatter(const int* __restrict__ ei, const float* __restrict__ ea,
                          const int* __restrict__ col_ptr, const int* __restrict__ pos,
                          int2* __restrict__ sw) {
    int e = blockIdx.x * 256 + threadIdx.x;
    if (e >= NE) return;
    int c = ei[NE + e];
    int p = col_ptr[c] + pos[e];
    sw[p] = make_int2(ei[e], __float_as_int(ea[e]));
}

// ---------- weighted degree (real count) + write zero pads ----------
__global__ void k_degsum(const int* __restrict__ col_ptr, const int* __restrict__ cnt,
                         int2* __restrict__ sw, float* __restrict__ dinv) {
    int i = blockIdx.x * 256 + threadIdx.x;
    if (i >= NN) return;
    int beg = col_ptr[i], mid = beg + cnt[i], end = col_ptr[i + 1];
    float s = 1.0f;  // self-loop weight
    for (int p = beg; p < mid; p++) s += __int_as_float(sw[p].y);
    for (int p = mid; p < end; p++) sw[p] = make_int2(0, 0);  // pad: src=0, w=0
    dinv[i] = rsqrtf(s);
}

// ---------- layer-0 transform: m = x @ W0 (K=5), bf16 output ----------
__global__ void k_gemm0(const float* __restrict__ x, const float* __restrict__ W,
                        unsigned* __restrict__ m32) {
    __shared__ float Ws[INF][HD];
    int t = threadIdx.x;  // 256
    for (int i = t; i < INF * HD; i += 256) ((float*)Ws)[i] = W[i];
    __syncthreads();
    int row = blockIdx.x * 4 + (t >> 6);
    if (row >= NN) return;
    int lane = t & 63;
    int c0 = 2 * lane;
    float xv[INF];
#pragma unroll
    for (int k = 0; k < INF; k++) xv[k] = x[row * INF + k];
    float a0 = 0.f, a1 = 0.f;
#pragma unroll
    for (int k = 0; k < INF; k++) {
        a0 += xv[k] * Ws[k][c0];
        a1 += xv[k] * Ws[k][c0 + 1];
    }
    m32[(size_t)row * 64 + lane] = bfpack(a0, a1);
}

// ---------- fused BN(prev)+SiLU + MFMA GEMM ----------
__global__ __launch_bounds__(256) void k_gemm128(
    const unsigned* __restrict__ h32, const float* __restrict__ stats,
    const float* __restrict__ gamma, const float* __restrict__ beta,
    const uint4* __restrict__ wfrag, unsigned short* __restrict__ m16) {
    __shared__ __align__(16) unsigned hs[64 * 64];  // 16 KB packed bf16
    __shared__ float sc[HD], sh[HD];
    int t = threadIdx.x;
    int r0 = blockIdx.x * BM;
    const float invn = 1.0f / NN;

    if (t < HD) {
        float mu = stats[t] * invn;
        float var = stats[HD + t] * invn - mu * mu;
        float s = gamma[t] * rsqrtf(var + BN_EPS);
        sc[t] = s;
        sh[t] = beta[t] - mu * s;
    }
    __syncthreads();

#pragma unroll
    for (int j = 0; j < 8; j++) {
        int g = j * 256 + t;      // uint2 slot 0..2047
        int r = g >> 5;           // row 0..63
        int u2 = g & 31;          // uint2 within row
        uint2 v = make_uint2(0u, 0u);
        if (r0 + r < NN) v = ((const uint2*)h32)[(size_t)(r0 + r) * 32 + u2];
        int c = u2 * 4;
        float y0 = sc[c] * bflo(v.x) + sh[c];
        float y1 = sc[c + 1] * bfhi(v.x) + sh[c + 1];
        float y2 = sc[c + 2] * bflo(v.y) + sh[c + 2];
        float y3 = sc[c + 3] * bfhi(v.y) + sh[c + 3];
        y0 = y0 / (1.f + __expf(-y0));
        y1 = y1 / (1.f + __expf(-y1));
        y2 = y2 / (1.f + __expf(-y2));
        y3 = y3 / (1.f + __expf(-y3));
        int slot = u2 >> 1, inner = (u2 & 1) * 2;
        int addr = r * 64 + ((slot ^ (r & 7)) << 2) + inner;
        hs[addr] = bfpack(y0, y1);
        hs[addr + 1] = bfpack(y2, y3);
    }
    __syncthreads();

    int w = t >> 6, l = t & 63;
    int lr = l & 15, lg = l >> 4;
    f32x4 acc[8];
#pragma unroll
    for (int i = 0; i < 8; i++) acc[i] = (f32x4){0.f, 0.f, 0.f, 0.f};

#pragma unroll
    for (int s = 0; s < 4; s++) {  // K steps of 32
        int arow = w * 16 + lr;
        int q = s * 4 + lg;
        short8v af = *reinterpret_cast<const short8v*>(
            &hs[arow * 64 + ((q ^ (arow & 7)) << 2)]);
#pragma unroll
        for (int tt = 0; tt < 8; tt++) {
            short8v bf = *reinterpret_cast<const short8v*>(&wfrag[(tt * 4 + s) * 64 + l]);
            acc[tt] = __builtin_amdgcn_mfma_f32_16x16x32_bf16(af, bf, acc[tt], 0, 0, 0);
        }
    }

    int baserow = r0 + w * 16 + lg * 4;
#pragma unroll
    for (int tt = 0; tt < 8; tt++) {
        int col = tt * 16 + lr;
#pragma unroll
        for (int reg = 0; reg < 4; reg++) {
            int row = baserow + reg;
            if (row < NN) m16[(size_t)row * HD + col] = bf1(acc[tt][reg]);
        }
    }
}

// ---------- sparse aggregation + fused BN stats: scalar edge records ----------
// beg/end/edge-records are wave-uniform -> SGPR path; gathers use saddr+lane.
template <bool NORM>
__global__ __launch_bounds__(1024, 8) void k_agg(
    const unsigned* __restrict__ m32, const int* __restrict__ col_ptr,
    int2* __restrict__ sw, const float* __restrict__ dinv,
    const float* __restrict__ bias, unsigned* __restrict__ hpre32,
    float* __restrict__ stats) {
    int t = threadIdx.x;
    int w = t >> 6, lane = t & 63;
    int gwave = blockIdx.x * 16 + w;
    float2 b = ((const float2*)bias)[lane];
    float ss0 = 0.f, ss1 = 0.f, sq0 = 0.f, sq1 = 0.f;

    for (int node = gwave; node < NN; node += AGW) {
        float di = dinv[node];
        unsigned sv = m32[(size_t)node * 64 + lane];
        float a0 = di * di * bflo(sv);
        float a1 = di * di * bfhi(sv);
        int beg = __builtin_amdgcn_readfirstlane(col_ptr[node]);
        int end = __builtin_amdgcn_readfirstlane(col_ptr[node + 1]);  // 8-aligned
        for (int p = beg; p < end; p += 8) {
            // 4 x int4 = 8 edge records from a wave-uniform address
            const int4* sp = (const int4*)(sw + p);
            int4 q0 = sp[0], q1 = sp[1], q2 = sp[2], q3 = sp[3];
            int s0 = __builtin_amdgcn_readfirstlane(q0.x);
            int s1 = __builtin_amdgcn_readfirstlane(q0.z);
            int s2 = __builtin_amdgcn_readfirstlane(q1.x);
            int s3 = __builtin_amdgcn_readfirstlane(q1.z);
            int s4 = __builtin_amdgcn_readfirstlane(q2.x);
            int s5 = __builtin_amdgcn_readfirstlane(q2.z);
            int s6 = __builtin_amdgcn_readfirstlane(q3.x);
            int s7 = __builtin_amdgcn_readfirstlane(q3.z);
            unsigned v0 = m32[(size_t)s0 * 64 + lane];
            unsigned v1 = m32[(size_t)s1 * 64 + lane];
            unsigned v2 = m32[(size_t)s2 * 64 + lane];
            unsigned v3 = m32[(size_t)s3 * 64 + lane];
            unsigned v4 = m32[(size_t)s4 * 64 + lane];
            unsigned v5 = m32[(size_t)s5 * 64 + lane];
            unsigned v6 = m32[(size_t)s6 * 64 + lane];
            unsigned v7 = m32[(size_t)s7 * 64 + lane];
            float w0 = __int_as_float(__builtin_amdgcn_readfirstlane(q0.y));
            float w1 = __int_as_float(__builtin_amdgcn_readfirstlane(q0.w));
            float w2 = __int_as_float(__builtin_amdgcn_readfirstlane(q1.y));
            float w3 = __int_as_float(__builtin_amdgcn_readfirstlane(q1.w));
            float w4 = __int_as_float(__builtin_amdgcn_readfirstlane(q2.y));
            float w5 = __int_as_float(__builtin_amdgcn_readfirstlane(q2.w));
            float w6 = __int_as_float(__builtin_amdgcn_readfirstlane(q3.y));
            float w7 = __int_as_float(__builtin_amdgcn_readfirstlane(q3.w));
            if (NORM) {
                w0 = dinv[s0] * w0 * di;
                w1 = dinv[s1] * w1 * di;
                w2 = dinv[s2] * w2 * di;
                w3 = dinv[s3] * w3 * di;
                w4 = dinv[s4] * w4 * di;
                w5 = dinv[s5] * w5 * di;
                w6 = dinv[s6] * w6 * di;
                w7 = dinv[s7] * w7 * di;
                if (lane == 0) {  // write normalized weights back for layers 1..3
                    sw[p].y = __float_as_int(w0);
                    sw[p + 1].y = __float_as_int(w1);
                    sw[p + 2].y = __float_as_int(w2);
                    sw[p + 3].y = __float_as_int(w3);
                    sw[p + 4].y = __float_as_int(w4);
                    sw[p + 5].y = __float_as_int(w5);
                    sw[p + 6].y = __float_as_int(w6);
                    sw[p + 7].y = __float_as_int(w7);
                }
            }
            a0 += w0 * bflo(v0) + w1 * bflo(v1) + w2 * bflo(v2) + w3 * bflo(v3);
            a1 += w0 * bfhi(v0) + w1 * bfhi(v1) + w2 * bfhi(v2) + w3 * bfhi(v3);
            a0 += w4 * bflo(v4) + w5 * bflo(v5) + w6 * bflo(v6) + w7 * bflo(v7);
            a1 += w4 * bfhi(v4) + w5 * bfhi(v5) + w6 * bfhi(v6) + w7 * bfhi(v7);
        }
        unsigned pk = bfpack(a0 + b.x, a1 + b.y);
        hpre32[(size_t)node * 64 + lane] = pk;
        float r0 = bflo(pk), r1 = bfhi(pk);
        ss0 += r0; sq0 += r0 * r0;
        ss1 += r1; sq1 += r1 * r1;
    }

    // fused BN stats: 16-wave LDS combine, then one atomic per stat slot
    __shared__ float lsum[16][HD];
    __shared__ float lsqr[16][HD];
    lsum[w][2 * lane] = ss0;
    lsum[w][2 * lane + 1] = ss1;
    lsqr[w][2 * lane] = sq0;
    lsqr[w][2 * lane + 1] = sq1;
    __syncthreads();
    if (t < HD) {
        float s = 0.f;
#pragma unroll
        for (int i = 0; i < 16; i++) s += lsum[i][t];
        atomicAdd(&stats[t], s);
    } else if (t < 2 * HD) {
        int c = t - HD;
        float q = 0.f;
#pragma unroll
        for (int i = 0; i < 16; i++) q += lsqr[i][c];
        atomicAdd(&stats[HD + c], q);
    }
}

// ---------- pooling stage 1 (fused final BN+SiLU), bf16 input ----------
__global__ void k_poolp(const unsigned* __restrict__ h32, const float* __restrict__ stats,
                        const float* __restrict__ gamma, const float* __restrict__ beta,
                        const int* __restrict__ gstart, float* __restrict__ ppool) {
    int g = blockIdx.x / PP, p = blockIdx.x % PP;
    int t = threadIdx.x;          // 256
    int c4 = t & 31;              // 4-channel group
    int ro = t >> 5;
    const float invn = 1.0f / NN;
    float sc[4], sh[4];
#pragma unroll
    for (int q = 0; q < 4; q++) {
        int c = c4 * 4 + q;
        float mu = stats[c] * invn;
        float var = stats[HD + c] * invn - mu * mu;
        float s = gamma[c] * rsqrtf(var + BN_EPS);
        sc[q] = s;
        sh[q] = beta[c] - mu * s;
    }
    int beg = gstart[g], end = gstart[g + 1];
    const uint2* h2 = (const uint2*)h32;
    float4 acc = make_float4(0.f, 0.f, 0.f, 0.f);
    for (int r = beg + p * 8 + ro; r < end; r += PP * 8) {
        uint2 u = h2[(size_t)r * 32 + c4];
        float vals[4] = {bflo(u.x), bfhi(u.x), bflo(u.y), bfhi(u.y)};
#pragma unroll
        for (int q = 0; q < 4; q++) {
            float y = sc[q] * vals[q] + sh[q];
            (&acc.x)[q] += y / (1.f + __expf(-y));
        }
    }
    __shared__ float4 sm[256];
    sm[t] = acc;
    __syncthreads();
    if (t < 128) {
        float4 o = sm[t + 128];
        sm[t].x += o.x; sm[t].y += o.y; sm[t].z += o.z; sm[t].w += o.w;
    }
    __syncthreads();
    if (t < 64) {
        float4 o = sm[t + 64];
        sm[t].x += o.x; sm[t].y += o.y; sm[t].z += o.z; sm[t].w += o.w;
    }
    __syncthreads();
    if (t < 32) {
        float4 o = sm[t + 32];
        float4 r = sm[t];
        r.x += o.x; r.y += o.y; r.z += o.z; r.w += o.w;
        ((float4*)ppool)[(size_t)blockIdx.x * 32 + t] = r;
    }
}

// ---------- pooling stage 2 + head MLP fused ----------
__global__ void k_pool_head(const float* __restrict__ ppool, const int* __restrict__ gstart,
                            const float* __restrict__ fc1w, const float* __restrict__ fc1b,
                            const float* __restrict__ fc2w, const float* __restrict__ fc2b,
                            float* __restrict__ out) {
    int g = blockIdx.x;
    int t = threadIdx.x;  // 128
    __shared__ float pa[HD];
    float s = 0.f;
    for (int p = 0; p < PP; p++) s += ppool[(size_t)(g * PP + p) * HD + t];
    float cnt = (float)(gstart[g + 1] - gstart[g]);
    pa[t] = s / fmaxf(cnt, 1.0f);
    __syncthreads();
    if (t < 64) {
        float a = fc1b[t];
        for (int k = 0; k < HD; k++) a += pa[k] * fc1w[k * 64 + t];
        a = a / (1.f + __expf(-a));  // SiLU
        float v = a * fc2w[t];
        for (int off = 32; off > 0; off >>= 1) v += __shfl_down(v, off);
        if (t == 0) out[g] = 1.f / (1.f + __expf(-(v + fc2b[0])));
    }
}

extern "C" void kernel_launch(void* const* d_in, const int* in_sizes, int n_in,
                              void* d_out, int out_size, void* d_ws, size_t ws_size,
                              hipStream_t stream) {
    const float* x = (const float*)d_in[0];
    const int* ei = (const int*)d_in[1];  // [2, E]: row=ei[0..E), col=ei[E..2E)
    const float* ea = (const float*)d_in[2];
    const int* batch = (const int*)d_in[3];
    const float* conv0_w = (const float*)d_in[5];
    const float* conv0_b = (const float*)d_in[6];
    const float* conv_ws = (const float*)d_in[7];
    const float* conv_bs = (const float*)d_in[8];
    const float* bn_gamma = (const float*)d_in[9];
    const float* bn_beta = (const float*)d_in[10];
    const float* fc1w = (const float*)d_in[11];
    const float* fc1b = (const float*)d_in[12];
    const float* fc2w = (const float*)d_in[13];
    const float* fc2b = (const float*)d_in[14];
    float* out = (float*)d_out;

    char* ws = (char*)d_ws;
    size_t off = 0;
    auto alloc = [&](size_t bytes) -> char* {
        char* p = ws + off;
        off = (off + bytes + 255) & ~(size_t)255;
        return p;
    };
    float* dinv = (float*)alloc(NN * 4);
    int* fill = (int*)alloc(NN * 4);
    int* col_ptr = (int*)alloc((NN + 1) * 4);
    int* pos = (int*)alloc(NE * 4);
    int2* sw = (int2*)alloc(((size_t)NE + 8 * NN) * 8);  // padded CSR
    unsigned* mbuf = (unsigned*)alloc((size_t)NN * HD * 2);
    unsigned* hA = (unsigned*)alloc((size_t)NN * HD * 2);
    unsigned* hB = (unsigned*)alloc((size_t)NN * HD * 2);
    unsigned* wbf = (unsigned*)alloc((size_t)NWFU * 4);
    float* stats = (float*)alloc(4 * 2 * HD * 4);
    float* ppool = (float*)alloc((size_t)NGR * PP * HD * 4);
    int* gstart = (int*)alloc((NGR + 1) * 4);
    int* bsum = (int*)alloc(SCB * 4);
    int* boff = (int*)alloc((SCB + 1) * 4);

    k_init<<<(NN + 255) / 256, 256, 0, stream>>>(fill, stats, conv_ws, wbf);
    k_pos<<<(NE + 255) / 256, 256, 0, stream>>>(ei, fill, pos);
    k_scan1<<<SCB, SCT, 0, stream>>>(fill, bsum);
    k_scan2_gb<<<2, SCB, 0, stream>>>(bsum, boff, batch, gstart);
    k_scan3<<<SCB, SCT, 0, stream>>>(fill, boff, col_ptr);
    k_scatter<<<(NE + 255) / 256, 256, 0, stream>>>(ei, ea, col_ptr, pos, sw);
    k_degsum<<<(NN + 255) / 256, 256, 0, stream>>>(col_ptr, fill, sw, dinv);

    float* st0 = stats;
    float* st1 = stats + 2 * HD;
    float* st2 = stats + 4 * HD;
    float* st3 = stats + 6 * HD;
    const int NG128 = (NN + BM - 1) / BM;
    const uint4* wf = (const uint4*)wbf;  // 2048 uint4 per layer

    // L0 (agg fuses weight normalization + BN0 stats)
    k_gemm0<<<(NN + 3) / 4, 256, 0, stream>>>(x, conv0_w, mbuf);
    k_agg<true><<<AGB, 1024, 0, stream>>>(mbuf, col_ptr, sw, dinv, conv0_b, hA, st0);
    // L1
    k_gemm128<<<NG128, 256, 0, stream>>>(hA, st0, bn_gamma, bn_beta, wf,
                                         (unsigned short*)mbuf);
    k_agg<false><<<AGB, 1024, 0, stream>>>(mbuf, col_ptr, sw, dinv, conv_bs, hB, st1);
    // L2
    k_gemm128<<<NG128, 256, 0, stream>>>(hB, st1, bn_gamma + HD, bn_beta + HD, wf + 2048,
                                         (unsigned short*)mbuf);
    k_agg<false><<<AGB, 1024, 0, stream>>>(mbuf, col_ptr, sw, dinv, conv_bs + HD, hA, st2);
    // L3
    k_gemm128<<<NG128, 256, 0, stream>>>(hA, st2, bn_gamma + 2 * HD, bn_beta + 2 * HD,
                                         wf + 4096, (unsigned short*)mbuf);
    k_agg<false><<<AGB, 1024, 0, stream>>>(mbuf, col_ptr, sw, dinv, conv_bs + 2 * HD, hB,
                                           st3);
    // fused final BN+SiLU + pool + head
    k_poolp<<<NGR * PP, 256, 0, stream>>>(hB, st3, bn_gamma + 3 * HD, bn_beta + 3 * HD,
                                          gstart, ppool);
    k_pool_head<<<NGR, HD, 0, stream>>>(ppool, gstart, fc1w, fc1b, fc2w, fc2b, out);
}